// Round 5
// baseline (509.737 us; speedup 1.0000x reference)
//
#include <hip/hip_runtime.h>

// VQSpeaker: obs[32,2048,128] -> 3-layer MLP -> x[65536,64] -> VQ argmin over
// codebook[2048,64] -> (msg = codebook[idx], idx, cmt_loss).
//
// Round 5 vq: ONE MFMA pass, fp16 2-product split ((xh+xl)*ch, fp32 acc),
// per-slot top-2 + argmax tracking, in-wave merge, certified gap check
// (eps <= 2^-11 * |x| * max|c| + safety); rare wave-cooperative exact fp32
// fallback. Codebook-hi frags staged in LDS chunks of 8 tiles, double-buffered
// (17 barriers total). 64 pts/block -> 1024 blocks -> 4 blocks/CU.
//
// d_out layout (float32): msg[4194304] | idx[65536] (as float) | loss[1]
// d_ws: e2[2048] | e2h[2048] | maxe2_bits | pad | cbh16 frags (256 KB)

#define NPTS    65536
#define IN_DIM  128
#define HID     64
#define OUT_DIM 64
#define CB_N    2048
#define MSG_ELEMS (NPTS * OUT_DIM)
#define LOSS_SCALE (1.0f / 4194304.0f)

typedef _Float16 half8 __attribute__((ext_vector_type(8)));
typedef __attribute__((ext_vector_type(4))) float f32x4;

__global__ void zero_kernel(float* __restrict__ loss, unsigned* __restrict__ maxbits) {
    *loss = 0.0f;
    *maxbits = 0u;
}

__global__ __launch_bounds__(256) void e2_kernel(
    const float* __restrict__ codebook, float* __restrict__ e2,
    float* __restrict__ e2h, unsigned* __restrict__ maxbits)
{
    const int c = blockIdx.x * 256 + threadIdx.x;
    const float4* row = (const float4*)(codebook + (long)c * OUT_DIM);
    float s = 0.0f;
    #pragma unroll
    for (int m = 0; m < 16; ++m) {
        const float4 v = row[m];
        s += v.x * v.x + v.y * v.y + v.z * v.z + v.w * v.w;
    }
    e2[c] = s;
    e2h[c] = 0.5f * s;
    float mx = s;
    #pragma unroll
    for (int off = 32; off > 0; off >>= 1) mx = fmaxf(mx, __shfl_xor(mx, off, 64));
    if ((threadIdx.x & 63) == 0) atomicMax(maxbits, __float_as_uint(mx));
}

// Permute codebook into MFMA B-fragment order (R3-verified indexing), fp16.
// (tile,half,lane,j): cb[tile*16+(lane&15)][half*32+(lane>>4)*8+j]
// dst halfs = ((tile*2+half)*64 + lane)*8 + j  -> tile*1024 + half*512 + lane*8
__global__ __launch_bounds__(256) void prep_kernel(
    const float* __restrict__ cb, _Float16* __restrict__ cbh16)
{
    const int id = blockIdx.x * 256 + threadIdx.x;  // (code n, half hh)
    const int n = id >> 1, hh = id & 1;
    const int tl = n >> 4, l15 = n & 15;
    const float* src = cb + (long)n * OUT_DIM + hh * 32;
    #pragma unroll
    for (int quad = 0; quad < 4; ++quad) {
        half8 hi;
        #pragma unroll
        for (int j = 0; j < 8; ++j) hi[j] = (_Float16)src[quad * 8 + j];
        const long dst = ((long)(tl * 2 + hh) * 64 + quad * 16 + l15) * 8;
        *(half8*)(cbh16 + dst) = hi;
    }
}

// ---------------- MLP: unchanged (passing numerics) ----------------
__global__ __launch_bounds__(256) void mlp_kernel(
    const float* __restrict__ obs,
    const float* __restrict__ W1, const float* __restrict__ b1,
    const float* __restrict__ W2, const float* __restrict__ b2,
    const float* __restrict__ W3, const float* __restrict__ b3,
    float* __restrict__ xout)
{
    __shared__ float wbuf[8448];
    __shared__ float h1_s[64 * 68];
    __shared__ float bias_s[64];

    const int t = threadIdx.x;
    const long base = (long)blockIdx.x * 64;
    const int pt = t & 15, jt = t >> 4;

    #pragma unroll
    for (int m = 0; m < 32; ++m) wbuf[t + 256 * m] = W1[t + 256 * m];
    if (t < 64) bias_s[t] = b1[t];
    __syncthreads();

    float acc[4][4];
    #pragma unroll
    for (int i = 0; i < 4; ++i)
        #pragma unroll
        for (int j = 0; j < 4; ++j) acc[i][j] = 0.0f;

    const float* obs_rows[4];
    #pragma unroll
    for (int i = 0; i < 4; ++i) obs_rows[i] = obs + (base + pt + 16 * i) * IN_DIM;

    for (int k = 0; k < 128; k += 4) {
        float4 ov[4];
        #pragma unroll
        for (int i = 0; i < 4; ++i) ov[i] = *(const float4*)(obs_rows[i] + k);
        #pragma unroll
        for (int jj = 0; jj < 4; ++jj) {
            const int j = jt + 16 * jj;
            const float w0 = wbuf[(k + 0) * 64 + j];
            const float w1v = wbuf[(k + 1) * 64 + j];
            const float w2v = wbuf[(k + 2) * 64 + j];
            const float w3v = wbuf[(k + 3) * 64 + j];
            #pragma unroll
            for (int i = 0; i < 4; ++i) {
                acc[i][jj] = fmaf(ov[i].x, w0, acc[i][jj]);
                acc[i][jj] = fmaf(ov[i].y, w1v, acc[i][jj]);
                acc[i][jj] = fmaf(ov[i].z, w2v, acc[i][jj]);
                acc[i][jj] = fmaf(ov[i].w, w3v, acc[i][jj]);
            }
        }
    }
    #pragma unroll
    for (int i = 0; i < 4; ++i)
        #pragma unroll
        for (int jj = 0; jj < 4; ++jj) {
            const float v = acc[i][jj] + bias_s[jt + 16 * jj];
            h1_s[(pt + 16 * i) * 68 + jt + 16 * jj] = v > 0.0f ? v : 0.0f;
        }
    __syncthreads();

    #pragma unroll
    for (int m = 0; m < 16; ++m) wbuf[t + 256 * m] = W2[t + 256 * m];
    if (t < 64) bias_s[t] = b2[t];
    __syncthreads();

    float* h2_s = wbuf + 4096;
    #pragma unroll
    for (int i = 0; i < 4; ++i)
        #pragma unroll
        for (int j = 0; j < 4; ++j) acc[i][j] = 0.0f;
    for (int k = 0; k < 64; k += 4) {
        float4 hv[4];
        #pragma unroll
        for (int i = 0; i < 4; ++i) hv[i] = *(const float4*)&h1_s[(pt + 16 * i) * 68 + k];
        #pragma unroll
        for (int jj = 0; jj < 4; ++jj) {
            const int j = jt + 16 * jj;
            const float w0 = wbuf[(k + 0) * 64 + j];
            const float w1v = wbuf[(k + 1) * 64 + j];
            const float w2v = wbuf[(k + 2) * 64 + j];
            const float w3v = wbuf[(k + 3) * 64 + j];
            #pragma unroll
            for (int i = 0; i < 4; ++i) {
                acc[i][jj] = fmaf(hv[i].x, w0, acc[i][jj]);
                acc[i][jj] = fmaf(hv[i].y, w1v, acc[i][jj]);
                acc[i][jj] = fmaf(hv[i].z, w2v, acc[i][jj]);
                acc[i][jj] = fmaf(hv[i].w, w3v, acc[i][jj]);
            }
        }
    }
    #pragma unroll
    for (int i = 0; i < 4; ++i)
        #pragma unroll
        for (int jj = 0; jj < 4; ++jj) {
            const float v = acc[i][jj] + bias_s[jt + 16 * jj];
            h2_s[(pt + 16 * i) * 68 + jt + 16 * jj] = v > 0.0f ? v : 0.0f;
        }
    __syncthreads();

    #pragma unroll
    for (int m = 0; m < 16; ++m) wbuf[t + 256 * m] = W3[t + 256 * m];
    if (t < 64) bias_s[t] = b3[t];
    __syncthreads();

    #pragma unroll
    for (int i = 0; i < 4; ++i)
        #pragma unroll
        for (int j = 0; j < 4; ++j) acc[i][j] = 0.0f;
    for (int k = 0; k < 64; k += 4) {
        float4 hv[4];
        #pragma unroll
        for (int i = 0; i < 4; ++i) hv[i] = *(const float4*)&h2_s[(pt + 16 * i) * 68 + k];
        #pragma unroll
        for (int jj = 0; jj < 4; ++jj) {
            const int j = jt + 16 * jj;
            const float w0 = wbuf[(k + 0) * 64 + j];
            const float w1v = wbuf[(k + 1) * 64 + j];
            const float w2v = wbuf[(k + 2) * 64 + j];
            const float w3v = wbuf[(k + 3) * 64 + j];
            #pragma unroll
            for (int i = 0; i < 4; ++i) {
                acc[i][jj] = fmaf(hv[i].x, w0, acc[i][jj]);
                acc[i][jj] = fmaf(hv[i].y, w1v, acc[i][jj]);
                acc[i][jj] = fmaf(hv[i].z, w2v, acc[i][jj]);
                acc[i][jj] = fmaf(hv[i].w, w3v, acc[i][jj]);
            }
        }
    }
    #pragma unroll
    for (int i = 0; i < 4; ++i)
        #pragma unroll
        for (int jj = 0; jj < 4; ++jj)
            h1_s[(pt + 16 * i) * 68 + jt + 16 * jj] = acc[i][jj] + bias_s[jt + 16 * jj];
    __syncthreads();

    float4* og = (float4*)(xout + base * OUT_DIM);
    #pragma unroll
    for (int m = 0; m < 4; ++m) {
        const int v = t + 256 * m;
        const int p = v >> 4, k4 = v & 15;
        og[v] = *(const float4*)&h1_s[p * 68 + k4 * 4];
    }
}

// ---------------- VQ: 256 thr = 4 waves, 64 pts/block, 1024 blocks ----------
__global__ __launch_bounds__(256) void vq_f16(
    const float* __restrict__ cb,
    const _Float16* __restrict__ cbh16,
    const float* __restrict__ e2,
    const float* __restrict__ e2h,
    const unsigned* __restrict__ maxbits,
    float* __restrict__ msg,        // in: x, out: quantize
    float* __restrict__ idx_out,
    float* __restrict__ loss_out)
{
    __shared__ __align__(16) _Float16 dbuf[16384];   // 2 chunks x 8 tiles x 1024 half
    __shared__ int   idx_sh[64];
    __shared__ int   fb_list[64];
    __shared__ int   fb_cnt;
    __shared__ float wred[4];

    const int t = threadIdx.x;
    const int lane = t & 63;
    const int w = __builtin_amdgcn_readfirstlane(t >> 6);
    const int m = lane & 15, quad = lane >> 4;
    const long base = (long)blockIdx.x * 64;

    if (t == 0) fb_cnt = 0;

    // ---- A-frags: fp16 split of x[point = w*16+m][k = kh*32 + quad*8 + j] ----
    const float* xrow = msg + (base + w * 16 + m) * OUT_DIM;
    half8 ah[2], al[2];
    float xn2 = 0.0f;
    #pragma unroll
    for (int kh = 0; kh < 2; ++kh) {
        const float4 xa = *(const float4*)(xrow + kh * 32 + quad * 8);
        const float4 xb = *(const float4*)(xrow + kh * 32 + quad * 8 + 4);
        const float xs[8] = {xa.x, xa.y, xa.z, xa.w, xb.x, xb.y, xb.z, xb.w};
        #pragma unroll
        for (int j = 0; j < 8; ++j) {
            const _Float16 h = (_Float16)xs[j];
            ah[kh][j] = h;
            al[kh][j] = (_Float16)(xs[j] - (float)h);
            xn2 = fmaf(xs[j], xs[j], xn2);
        }
    }
    xn2 += __shfl_xor(xn2, 16, 64);
    xn2 += __shfl_xor(xn2, 32, 64);     // full |x_m|^2 in every lane of column m

    // ---- stage chunk 0 (8 tiles = 16 KB; wave w stages its 4 KB quarter) ----
    {
        const float4* src = (const float4*)(cbh16 + w * 2048);
        float4* dst = (float4*)(dbuf + w * 2048);
        #pragma unroll
        for (int i = 0; i < 4; ++i) dst[i * 64 + lane] = src[i * 64 + lane];
    }
    __syncthreads();

    float bd1[4], bd2[4];
    int   bi[4];
    #pragma unroll
    for (int r = 0; r < 4; ++r) { bd1[r] = -3.4e38f; bd2[r] = -3.4e38f; bi[r] = 0; }

    // ---- main loop: 16 chunks x 8 tiles, double-buffered ----
    for (int cc = 0; cc < 16; ++cc) {
        const int buf = cc & 1;
        float4 st[4];
        if (cc < 15) {
            const float4* src = (const float4*)(cbh16 + (cc + 1) * 8192 + w * 2048);
            #pragma unroll
            for (int i = 0; i < 4; ++i) st[i] = src[i * 64 + lane];
        }
        #pragma unroll
        for (int j = 0; j < 8; ++j) {
            const int tt = cc * 8 + j;
            const half8 bh0 = *(const half8*)(dbuf + buf * 8192 + j * 1024 + lane * 8);
            const half8 bh1 = *(const half8*)(dbuf + buf * 8192 + j * 1024 + 512 + lane * 8);
            const float e2h_v = e2h[tt * 16 + m];
            f32x4 acc = {0.0f, 0.0f, 0.0f, 0.0f};
            acc = __builtin_amdgcn_mfma_f32_16x16x32_f16(ah[0], bh0, acc, 0, 0, 0);
            acc = __builtin_amdgcn_mfma_f32_16x16x32_f16(al[0], bh0, acc, 0, 0, 0);
            acc = __builtin_amdgcn_mfma_f32_16x16x32_f16(ah[1], bh1, acc, 0, 0, 0);
            acc = __builtin_amdgcn_mfma_f32_16x16x32_f16(al[1], bh1, acc, 0, 0, 0);
            const int code = tt * 16 + m;
            #pragma unroll
            for (int r = 0; r < 4; ++r) {
                const float u = acc[r] - e2h_v;       // s' = x.c - e2/2 (max == argmin d)
                const bool gt = u > bd1[r];           // strict: keeps lowest code on approx tie
                bd2[r] = fmaxf(bd2[r], fminf(bd1[r], u));
                bd1[r] = fmaxf(bd1[r], u);
                bi[r]  = gt ? code : bi[r];
            }
        }
        if (cc < 15) {
            float4* dst = (float4*)(dbuf + (1 - buf) * 8192 + w * 2048);
            #pragma unroll
            for (int i = 0; i < 4; ++i) dst[i * 64 + lane] = st[i];
        }
        __syncthreads();
    }

    // ---- in-wave merge over the 16 code-columns (lanes share quad group) ----
    #pragma unroll
    for (int off = 1; off < 16; off <<= 1) {
        #pragma unroll
        for (int r = 0; r < 4; ++r) {
            const float obd1 = __shfl_xor(bd1[r], off, 64);
            const float obd2 = __shfl_xor(bd2[r], off, 64);
            const int   obi  = __shfl_xor(bi[r],  off, 64);
            const bool take = (obd1 > bd1[r]) || (obd1 == bd1[r] && obi < bi[r]);
            const float nbd2 = fmaxf(fminf(bd1[r], obd1), fmaxf(bd2[r], obd2));
            bd1[r] = take ? obd1 : bd1[r];
            bi[r]  = take ? obi  : bi[r];
            bd2[r] = nbd2;
        }
    }
    // |x|^2 of point quad*4+r lives in column-lane (quad*4+r)
    float xn2p[4];
    #pragma unroll
    for (int r = 0; r < 4; ++r) xn2p[r] = __shfl(xn2, quad * 4 + r, 64);

    const float maxe2 = __uint_as_float(*maxbits);
    if (m == 0) {
        #pragma unroll
        for (int r = 0; r < 4; ++r) {
            const int p = w * 16 + quad * 4 + r;
            // certified fp16-split error bound: 2^-11 * |x| * max|c| + safety
            const float eps = 4.8828125e-4f * sqrtf(xn2p[r] * maxe2) + 1e-3f;
            idx_sh[p] = bi[r];
            if (bd1[r] - bd2[r] > 2.0f * eps) {
                idx_out[base + p] = (float)bi[r];     // provably the exact argmin
            } else {
                fb_list[atomicAdd(&fb_cnt, 1)] = p;   // rare: exact rescan below
            }
        }
    }
    __syncthreads();

    // ---- fallback: wave-cooperative exact fp32 scan for flagged points ----
    const int nfb = fb_cnt;
    for (int e = w; e < nfb; e += 4) {
        const int p = fb_list[e];
        const float4* xp = (const float4*)(msg + (base + p) * OUT_DIM);  // still x
        float bd = 3.4e38f; int bidx = 1 << 30;
        for (int c = lane; c < CB_N; c += 64) {
            const float4* cp = (const float4*)(cb + (long)c * OUT_DIM);
            float a0 = 0.0f, a1 = 0.0f;
            #pragma unroll
            for (int k = 0; k < 16; ++k) {
                const float4 xv = xp[k], cv = cp[k];
                a0 = fmaf(xv.x, cv.x, a0); a1 = fmaf(xv.y, cv.y, a1);
                a0 = fmaf(xv.z, cv.z, a0); a1 = fmaf(xv.w, cv.w, a1);
            }
            const float d = fmaf(-2.0f, a0 + a1, e2[c]);
            if (d < bd) { bd = d; bidx = c; }         // ascending per lane
        }
        #pragma unroll
        for (int off = 1; off < 64; off <<= 1) {
            const float od = __shfl_xor(bd, off, 64);
            const int   oi = __shfl_xor(bidx, off, 64);
            const bool take = (od < bd) || (od == bd && oi < bidx);
            bd   = take ? od : bd;
            bidx = take ? oi : bidx;
        }
        if (lane == 0) {
            idx_sh[p] = bidx;
            idx_out[base + p] = (float)bidx;
        }
    }
    __syncthreads();

    // ---- gather q, write msg, accumulate loss ----
    float lsum = 0.0f;
    float4* xg = (float4*)(msg + base * OUT_DIM);
    #pragma unroll
    for (int mm = 0; mm < 4; ++mm) {
        const int v = t + 256 * mm;
        const int p = v >> 4, k4 = v & 15;
        const int code = idx_sh[p];
        const float4 q = ((const float4*)(cb + (long)code * OUT_DIM))[k4];
        const float4 xv = xg[v];
        const float dx = q.x - xv.x, dy = q.y - xv.y;
        const float dz = q.z - xv.z, dw2 = q.w - xv.w;
        lsum += dx * dx + dy * dy + dz * dz + dw2 * dw2;
        xg[v] = q;
    }
    #pragma unroll
    for (int off = 32; off > 0; off >>= 1) lsum += __shfl_down(lsum, off, 64);
    if (lane == 0) wred[w] = lsum;
    __syncthreads();
    if (t == 0)
        atomicAdd(loss_out, (wred[0] + wred[1] + wred[2] + wred[3]) * LOSS_SCALE);
}

extern "C" void kernel_launch(void* const* d_in, const int* in_sizes, int n_in,
                              void* d_out, int out_size, void* d_ws, size_t ws_size,
                              hipStream_t stream) {
    const float* obs = (const float*)d_in[0];
    const float* W1  = (const float*)d_in[1];
    const float* b1  = (const float*)d_in[2];
    const float* W2  = (const float*)d_in[3];
    const float* b2  = (const float*)d_in[4];
    const float* W3  = (const float*)d_in[5];
    const float* b3  = (const float*)d_in[6];
    const float* cb  = (const float*)d_in[7];

    float* out  = (float*)d_out;
    float* msg  = out;                        // also x staging
    float* idxf = out + MSG_ELEMS;
    float* loss = out + MSG_ELEMS + NPTS;

    float*    e2      = (float*)d_ws;                      // [0, 2048)
    float*    e2h     = e2 + 2048;                         // [2048, 4096)
    unsigned* maxb    = (unsigned*)(e2 + 4096);            // 1 slot
    _Float16* cbh16   = (_Float16*)((char*)d_ws + 16640);  // 256 KB, 16B-aligned

    zero_kernel<<<1, 1, 0, stream>>>(loss, maxb);
    e2_kernel<<<CB_N / 256, 256, 0, stream>>>(cb, e2, e2h, maxb);
    prep_kernel<<<16, 256, 0, stream>>>(cb, cbh16);
    mlp_kernel<<<NPTS / 64, 256, 0, stream>>>(obs, W1, b1, W2, b2, W3, b3, msg);
    vq_f16<<<NPTS / 64, 256, 0, stream>>>(cb, cbh16, e2, e2h, maxb, msg, idxf, loss);
}

// Round 7
// 507.657 us; speedup vs baseline: 1.0041x; 1.0041x over previous
//
#include <hip/hip_runtime.h>

// VQSpeaker: obs[32,2048,128] -> 3-layer MLP -> x[65536,64] -> VQ argmin over
// codebook[2048,64] -> (msg = codebook[idx], idx, cmt_loss).
//
// Round 7 vq: R6's decoupled-wave structure (no barriers / no global loads in
// the hot loop, distance-2 register prefetch of fp16 B-frags, 2 M-tiles/wave)
// with R5's PROVEN certification numerics (acc init 0, u = acc - e2/2 from
// LDS, eps = 2^-11 * |x| * max|c| + 1e-3, shuffles outside divergence).
//
// d_out layout (float32): msg[4194304] | idx[65536] (as float) | loss[1]
// d_ws: e2[2048] f32 | maxe2 bits | pad | cbh16 frags (256 KB)

#define NPTS    65536
#define IN_DIM  128
#define HID     64
#define OUT_DIM 64
#define CB_N    2048
#define MSG_ELEMS (NPTS * OUT_DIM)
#define LOSS_SCALE (1.0f / 4194304.0f)

typedef _Float16 half8 __attribute__((ext_vector_type(8)));
typedef __attribute__((ext_vector_type(4))) float f32x4;

__global__ void zero_kernel(float* __restrict__ loss, unsigned* __restrict__ maxb) {
    *loss = 0.0f;
    *maxb = 0u;
}

// e2 per code + max over codes of |c|^2 (for R5's certified bound)
__global__ __launch_bounds__(256) void e2_kernel(
    const float* __restrict__ codebook, float* __restrict__ e2,
    unsigned* __restrict__ maxb)
{
    const int c = blockIdx.x * 256 + threadIdx.x;
    const float4* row = (const float4*)(codebook + (long)c * OUT_DIM);
    float s = 0.0f;
    #pragma unroll
    for (int m = 0; m < 16; ++m) {
        const float4 v = row[m];
        s += v.x * v.x + v.y * v.y + v.z * v.z + v.w * v.w;
    }
    e2[c] = s;
    float mx = s;
    #pragma unroll
    for (int off = 32; off > 0; off >>= 1) mx = fmaxf(mx, __shfl_xor(mx, off, 64));
    if ((threadIdx.x & 63) == 0) atomicMax(maxb, __float_as_uint(mx));
}

// Permute codebook into MFMA B-fragment order (R3/R5-verified indexing), fp16.
// (tile,half,lane,j): cb[tile*16+(lane&15)][half*32+(lane>>4)*8+j]
// dst = ((tile*2+half)*64 + lane)*8 + j
__global__ __launch_bounds__(256) void prep_kernel(
    const float* __restrict__ cb, _Float16* __restrict__ cbh16)
{
    const int id = blockIdx.x * 256 + threadIdx.x;  // (code n, half hh)
    const int n = id >> 1, hh = id & 1;
    const int tl = n >> 4, l15 = n & 15;
    const float* src = cb + (long)n * OUT_DIM + hh * 32;
    #pragma unroll
    for (int quad = 0; quad < 4; ++quad) {
        half8 hi;
        #pragma unroll
        for (int j = 0; j < 8; ++j) hi[j] = (_Float16)src[quad * 8 + j];
        const long dst = ((long)(tl * 2 + hh) * 64 + quad * 16 + l15) * 8;
        *(half8*)(cbh16 + dst) = hi;
    }
}

// ---------------- MLP: unchanged (passing numerics — DO NOT reorder fmaf) ----
__global__ __launch_bounds__(256) void mlp_kernel(
    const float* __restrict__ obs,
    const float* __restrict__ W1, const float* __restrict__ b1,
    const float* __restrict__ W2, const float* __restrict__ b2,
    const float* __restrict__ W3, const float* __restrict__ b3,
    float* __restrict__ xout)
{
    __shared__ float wbuf[8448];
    __shared__ float h1_s[64 * 68];
    __shared__ float bias_s[64];

    const int t = threadIdx.x;
    const long base = (long)blockIdx.x * 64;
    const int pt = t & 15, jt = t >> 4;

    #pragma unroll
    for (int m = 0; m < 32; ++m) wbuf[t + 256 * m] = W1[t + 256 * m];
    if (t < 64) bias_s[t] = b1[t];
    __syncthreads();

    float acc[4][4];
    #pragma unroll
    for (int i = 0; i < 4; ++i)
        #pragma unroll
        for (int j = 0; j < 4; ++j) acc[i][j] = 0.0f;

    const float* obs_rows[4];
    #pragma unroll
    for (int i = 0; i < 4; ++i) obs_rows[i] = obs + (base + pt + 16 * i) * IN_DIM;

    for (int k = 0; k < 128; k += 4) {
        float4 ov[4];
        #pragma unroll
        for (int i = 0; i < 4; ++i) ov[i] = *(const float4*)(obs_rows[i] + k);
        #pragma unroll
        for (int jj = 0; jj < 4; ++jj) {
            const int j = jt + 16 * jj;
            const float w0 = wbuf[(k + 0) * 64 + j];
            const float w1v = wbuf[(k + 1) * 64 + j];
            const float w2v = wbuf[(k + 2) * 64 + j];
            const float w3v = wbuf[(k + 3) * 64 + j];
            #pragma unroll
            for (int i = 0; i < 4; ++i) {
                acc[i][jj] = fmaf(ov[i].x, w0, acc[i][jj]);
                acc[i][jj] = fmaf(ov[i].y, w1v, acc[i][jj]);
                acc[i][jj] = fmaf(ov[i].z, w2v, acc[i][jj]);
                acc[i][jj] = fmaf(ov[i].w, w3v, acc[i][jj]);
            }
        }
    }
    #pragma unroll
    for (int i = 0; i < 4; ++i)
        #pragma unroll
        for (int jj = 0; jj < 4; ++jj) {
            const float v = acc[i][jj] + bias_s[jt + 16 * jj];
            h1_s[(pt + 16 * i) * 68 + jt + 16 * jj] = v > 0.0f ? v : 0.0f;
        }
    __syncthreads();

    #pragma unroll
    for (int m = 0; m < 16; ++m) wbuf[t + 256 * m] = W2[t + 256 * m];
    if (t < 64) bias_s[t] = b2[t];
    __syncthreads();

    float* h2_s = wbuf + 4096;
    #pragma unroll
    for (int i = 0; i < 4; ++i)
        #pragma unroll
        for (int j = 0; j < 4; ++j) acc[i][j] = 0.0f;
    for (int k = 0; k < 64; k += 4) {
        float4 hv[4];
        #pragma unroll
        for (int i = 0; i < 4; ++i) hv[i] = *(const float4*)&h1_s[(pt + 16 * i) * 68 + k];
        #pragma unroll
        for (int jj = 0; jj < 4; ++jj) {
            const int j = jt + 16 * jj;
            const float w0 = wbuf[(k + 0) * 64 + j];
            const float w1v = wbuf[(k + 1) * 64 + j];
            const float w2v = wbuf[(k + 2) * 64 + j];
            const float w3v = wbuf[(k + 3) * 64 + j];
            #pragma unroll
            for (int i = 0; i < 4; ++i) {
                acc[i][jj] = fmaf(hv[i].x, w0, acc[i][jj]);
                acc[i][jj] = fmaf(hv[i].y, w1v, acc[i][jj]);
                acc[i][jj] = fmaf(hv[i].z, w2v, acc[i][jj]);
                acc[i][jj] = fmaf(hv[i].w, w3v, acc[i][jj]);
            }
        }
    }
    #pragma unroll
    for (int i = 0; i < 4; ++i)
        #pragma unroll
        for (int jj = 0; jj < 4; ++jj) {
            const float v = acc[i][jj] + bias_s[jt + 16 * jj];
            h2_s[(pt + 16 * i) * 68 + jt + 16 * jj] = v > 0.0f ? v : 0.0f;
        }
    __syncthreads();

    #pragma unroll
    for (int m = 0; m < 16; ++m) wbuf[t + 256 * m] = W3[t + 256 * m];
    if (t < 64) bias_s[t] = b3[t];
    __syncthreads();

    #pragma unroll
    for (int i = 0; i < 4; ++i)
        #pragma unroll
        for (int j = 0; j < 4; ++j) acc[i][j] = 0.0f;
    for (int k = 0; k < 64; k += 4) {
        float4 hv[4];
        #pragma unroll
        for (int i = 0; i < 4; ++i) hv[i] = *(const float4*)&h2_s[(pt + 16 * i) * 68 + k];
        #pragma unroll
        for (int jj = 0; jj < 4; ++jj) {
            const int j = jt + 16 * jj;
            const float w0 = wbuf[(k + 0) * 64 + j];
            const float w1v = wbuf[(k + 1) * 64 + j];
            const float w2v = wbuf[(k + 2) * 64 + j];
            const float w3v = wbuf[(k + 3) * 64 + j];
            #pragma unroll
            for (int i = 0; i < 4; ++i) {
                acc[i][jj] = fmaf(hv[i].x, w0, acc[i][jj]);
                acc[i][jj] = fmaf(hv[i].y, w1v, acc[i][jj]);
                acc[i][jj] = fmaf(hv[i].z, w2v, acc[i][jj]);
                acc[i][jj] = fmaf(hv[i].w, w3v, acc[i][jj]);
            }
        }
    }
    #pragma unroll
    for (int i = 0; i < 4; ++i)
        #pragma unroll
        for (int jj = 0; jj < 4; ++jj)
            h1_s[(pt + 16 * i) * 68 + jt + 16 * jj] = acc[i][jj] + bias_s[jt + 16 * jj];
    __syncthreads();

    float4* og = (float4*)(xout + base * OUT_DIM);
    #pragma unroll
    for (int m = 0; m < 4; ++m) {
        const int v = t + 256 * m;
        const int p = v >> 4, k4 = v & 15;
        og[v] = *(const float4*)&h1_s[p * 68 + k4 * 4];
    }
}

#define MFMA16(A, B, C) __builtin_amdgcn_mfma_f32_16x16x32_f16(A, B, C, 0, 0, 0)

// ---------------- VQ: 256 thr = 4 waves, 128 pts/block, 512 blocks ----------
// Wave = 32 points (2 M-tiles) x all 2048 codes. No barriers / global loads
// in the tile loop; waves fully decoupled. Screen numerics == R5 (proven).
__global__ __launch_bounds__(256) void vq_v7(
    const float* __restrict__ cb,
    const _Float16* __restrict__ cbh16,
    const float* __restrict__ e2,
    const unsigned* __restrict__ maxb,
    float* __restrict__ msg,        // in: x, out: quantize
    float* __restrict__ idx_out,
    float* __restrict__ loss_out)
{
    __shared__ float e2h_s[2048];       // +e2/2 (exact halving)
    __shared__ int   idx_sh[128];
    __shared__ int   fb_list[128];
    __shared__ int   fb_cnt;
    __shared__ float wred[4];

    const int t = threadIdx.x, lane = t & 63, w = t >> 6;
    const int m = lane & 15, quad = lane >> 4;
    const long blk_base = (long)blockIdx.x * 128;
    const long pbase = blk_base + (long)w * 32;

    if (t == 0) fb_cnt = 0;

    // preload +e2/2 into LDS (once; hot loop reads LDS only)
    {
        const float4* s4 = (const float4*)e2;
        float4* d4 = (float4*)e2h_s;
        #pragma unroll
        for (int i = 0; i < 2; ++i) {
            const float4 v = s4[t + 256 * i];
            const float4 o = {0.5f * v.x, 0.5f * v.y, 0.5f * v.z, 0.5f * v.w};
            d4[t + 256 * i] = o;
        }
    }

    // A-frags (fp16 split) for 2 M-tiles; per-point |x|^2
    half8 ah[2][2], al[2][2];           // [mtile][khalf]
    float xn2[2];
    #pragma unroll
    for (int mt = 0; mt < 2; ++mt) {
        const float* xrow = msg + (pbase + mt * 16 + m) * OUT_DIM;
        xn2[mt] = 0.0f;
        #pragma unroll
        for (int kh = 0; kh < 2; ++kh) {
            const float4 xa = *(const float4*)(xrow + kh * 32 + quad * 8);
            const float4 xb = *(const float4*)(xrow + kh * 32 + quad * 8 + 4);
            const float xs[8] = {xa.x, xa.y, xa.z, xa.w, xb.x, xb.y, xb.z, xb.w};
            #pragma unroll
            for (int j = 0; j < 8; ++j) {
                const _Float16 h = (_Float16)xs[j];
                ah[mt][kh][j] = h;
                al[mt][kh][j] = (_Float16)(xs[j] - (float)h);
                xn2[mt] = fmaf(xs[j], xs[j], xn2[mt]);
            }
        }
        xn2[mt] += __shfl_xor(xn2[mt], 16, 64);
        xn2[mt] += __shfl_xor(xn2[mt], 32, 64);   // full |x|^2 in all lanes of column m
    }
    const float maxe2 = __uint_as_float(*maxb);
    __syncthreads();                    // e2h_s + fb_cnt visible

    float bd1[2][4], bd2[2][4];
    int   bi[2][4];
    #pragma unroll
    for (int mt = 0; mt < 2; ++mt)
        #pragma unroll
        for (int r = 0; r < 4; ++r) { bd1[mt][r] = -3.4e38f; bd2[mt][r] = -3.4e38f; bi[mt][r] = 0; }

    // ---- hot loop: 128 tiles, distance-2 register prefetch, LDS e2 only ----
    const _Float16* bp = cbh16 + (long)lane * 8;
    half8 c0 = *(const half8*)(bp);
    half8 c1 = *(const half8*)(bp + 512);
    half8 n0 = *(const half8*)(bp + 1024);
    half8 n1 = *(const half8*)(bp + 1536);

    for (int tt = 0; tt < 128; tt += 2) {
        const int p0 = (tt + 2) & 127, p1 = (tt + 3) & 127;
        const half8 f0 = *(const half8*)(bp + p0 * 1024);
        const half8 f1 = *(const half8*)(bp + p0 * 1024 + 512);
        const half8 g0 = *(const half8*)(bp + p1 * 1024);
        const half8 g1 = *(const half8*)(bp + p1 * 1024 + 512);

        #pragma unroll
        for (int u2 = 0; u2 < 2; ++u2) {
            const int ti = tt + u2;
            const half8 B0 = u2 ? n0 : c0;
            const half8 B1 = u2 ? n1 : c1;
            const float e2h_v = e2h_s[ti * 16 + m];
            const int code = ti * 16 + m;
            #pragma unroll
            for (int mt = 0; mt < 2; ++mt) {
                f32x4 acc = {0.0f, 0.0f, 0.0f, 0.0f};      // R5 numerics: init 0
                acc = MFMA16(ah[mt][0], B0, acc);
                acc = MFMA16(al[mt][0], B0, acc);
                acc = MFMA16(ah[mt][1], B1, acc);
                acc = MFMA16(al[mt][1], B1, acc);
                #pragma unroll
                for (int r = 0; r < 4; ++r) {
                    const float u = acc[r] - e2h_v;        // s' = x.c - e2/2
                    const bool gt = u > bd1[mt][r];        // strict: lowest code on tie
                    bd2[mt][r] = fmaxf(bd2[mt][r], fminf(bd1[mt][r], u));
                    bd1[mt][r] = fmaxf(bd1[mt][r], u);
                    bi[mt][r]  = gt ? code : bi[mt][r];
                }
            }
        }
        c0 = f0; c1 = f1; n0 = g0; n1 = g1;
    }

    // ---- merge over the 16 columns (lanes sharing quad group) ----
    #pragma unroll
    for (int off = 1; off < 16; off <<= 1) {
        #pragma unroll
        for (int mt = 0; mt < 2; ++mt)
            #pragma unroll
            for (int r = 0; r < 4; ++r) {
                const float obd1 = __shfl_xor(bd1[mt][r], off, 64);
                const float obd2 = __shfl_xor(bd2[mt][r], off, 64);
                const int   obi  = __shfl_xor(bi[mt][r],  off, 64);
                const bool take = (obd1 > bd1[mt][r]) ||
                                  (obd1 == bd1[mt][r] && obi < bi[mt][r]);
                const float nbd2 = fmaxf(fminf(bd1[mt][r], obd1),
                                         fmaxf(bd2[mt][r], obd2));
                bd1[mt][r] = take ? obd1 : bd1[mt][r];
                bi[mt][r]  = take ? obi  : bi[mt][r];
                bd2[mt][r] = nbd2;
            }
    }

    // |x|^2 of point row rr lives in lane rr; shuffles OUTSIDE divergence (R5)
    float xn2p[2][4];
    #pragma unroll
    for (int mt = 0; mt < 2; ++mt)
        #pragma unroll
        for (int r = 0; r < 4; ++r)
            xn2p[mt][r] = __shfl(xn2[mt], quad * 4 + r, 64);

    if (m == 0) {
        #pragma unroll
        for (int mt = 0; mt < 2; ++mt)
            #pragma unroll
            for (int r = 0; r < 4; ++r) {
                const int rr = quad * 4 + r;
                // R5-proven certified bound: 2^-11 * |x| * max|c| + 1e-3
                const float eps = 4.8828125e-4f * sqrtf(xn2p[mt][r] * maxe2) + 1e-3f;
                const int p = w * 32 + mt * 16 + rr;
                idx_sh[p] = bi[mt][r];
                if (!(bd1[mt][r] - bd2[mt][r] > 2.0f * eps))
                    fb_list[atomicAdd(&fb_cnt, 1)] = p;   // rare
            }
    }
    __syncthreads();

    // ---- fallback: wave-cooperative exact fp32 scan (cold path, R5-proven) --
    const int nfb = fb_cnt;
    for (int e = w; e < nfb; e += 4) {
        const int p = fb_list[e];
        const float4* xp4 = (const float4*)(msg + (blk_base + p) * OUT_DIM);
        float bd = 3.4e38f; int bidx = 1 << 30;
        for (int c = lane; c < CB_N; c += 64) {
            const float4* cp = (const float4*)(cb + (long)c * OUT_DIM);
            float a0 = 0.0f, a1 = 0.0f;
            #pragma unroll
            for (int k = 0; k < 16; ++k) {
                const float4 xv = xp4[k], cv = cp[k];
                a0 = fmaf(xv.x, cv.x, a0); a1 = fmaf(xv.y, cv.y, a1);
                a0 = fmaf(xv.z, cv.z, a0); a1 = fmaf(xv.w, cv.w, a1);
            }
            const float d = fmaf(-2.0f, a0 + a1, e2[c]);
            if (d < bd) { bd = d; bidx = c; }             // ascending per lane
        }
        #pragma unroll
        for (int off = 1; off < 64; off <<= 1) {
            const float od = __shfl_xor(bd, off, 64);
            const int   oi = __shfl_xor(bidx, off, 64);
            const bool take = (od < bd) || (od == bd && oi < bidx);
            bd   = take ? od : bd;
            bidx = take ? oi : bidx;
        }
        if (lane == 0) idx_sh[p] = bidx;
    }
    __syncthreads();

    if (t < 128) idx_out[blk_base + t] = (float)idx_sh[t];

    // ---- gather q, write msg, accumulate loss ----
    float lsum = 0.0f;
    float4* xg = (float4*)(msg + blk_base * OUT_DIM);
    #pragma unroll
    for (int mm = 0; mm < 8; ++mm) {
        const int v = t + 256 * mm;
        const int p = v >> 4, k4 = v & 15;
        const int code = idx_sh[p];
        const float4 q = ((const float4*)(cb + (long)code * OUT_DIM))[k4];
        const float4 xv = xg[v];
        const float dx = q.x - xv.x, dy = q.y - xv.y;
        const float dz = q.z - xv.z, dw2 = q.w - xv.w;
        lsum += dx * dx + dy * dy + dz * dz + dw2 * dw2;
        xg[v] = q;
    }
    #pragma unroll
    for (int off = 32; off > 0; off >>= 1) lsum += __shfl_down(lsum, off, 64);
    if (lane == 0) wred[w] = lsum;
    __syncthreads();
    if (t == 0)
        atomicAdd(loss_out, (wred[0] + wred[1] + wred[2] + wred[3]) * LOSS_SCALE);
}

extern "C" void kernel_launch(void* const* d_in, const int* in_sizes, int n_in,
                              void* d_out, int out_size, void* d_ws, size_t ws_size,
                              hipStream_t stream) {
    const float* obs = (const float*)d_in[0];
    const float* W1  = (const float*)d_in[1];
    const float* b1  = (const float*)d_in[2];
    const float* W2  = (const float*)d_in[3];
    const float* b2  = (const float*)d_in[4];
    const float* W3  = (const float*)d_in[5];
    const float* b3  = (const float*)d_in[6];
    const float* cb  = (const float*)d_in[7];

    float* out  = (float*)d_out;
    float* msg  = out;                        // also x staging
    float* idxf = out + MSG_ELEMS;
    float* loss = out + MSG_ELEMS + NPTS;

    float*    e2    = (float*)d_ws;                      // 8 KB
    unsigned* maxb  = (unsigned*)((char*)d_ws + 8192);
    _Float16* cbh16 = (_Float16*)((char*)d_ws + 12288);  // 256 KB, aligned

    zero_kernel<<<1, 1, 0, stream>>>(loss, maxb);
    e2_kernel<<<CB_N / 256, 256, 0, stream>>>(cb, e2, maxb);
    prep_kernel<<<16, 256, 0, stream>>>(cb, cbh16);
    mlp_kernel<<<NPTS / 64, 256, 0, stream>>>(obs, W1, b1, W2, b2, W3, b3, msg);
    vq_v7<<<NPTS / 128, 256, 0, stream>>>(cb, cbh16, e2, maxb, msg, idxf, loss);
}

// Round 8
// 250.595 us; speedup vs baseline: 2.0341x; 2.0258x over previous
//
#include <hip/hip_runtime.h>

// VQSpeaker: obs[32,2048,128] -> 3-layer MLP -> x[65536,64] -> VQ argmin over
// codebook[2048,64] -> (msg = codebook[idx], idx, cmt_loss).
//
// Round 8: vq = R3's kernel VERBATIM (best measured: 156 us, passed).
//          mlp -> MFMA fp16 3-product split (ah*wh + al*wh + ah*wl, fp32 acc;
//          dropped term <= 2^-22 relative — below fp32 reorder noise).
//          Weights pre-permuted to B-frag order; activations round-trip
//          wave-locally through LDS (no barriers until final store).
//
// d_out layout (float32): msg[4194304] | idx[65536] (as float) | loss[1]
// d_ws: e2[2048] | cbh bf16 256KB | cbl bf16 256KB | w1h/w1l 16KB ea |
//       w2h/w2l/w3h/w3l 8KB ea   (total ~584 KB)

#define NPTS    65536
#define IN_DIM  128
#define HID     64
#define OUT_DIM 64
#define CB_N    2048
#define MSG_ELEMS (NPTS * OUT_DIM)
#define LOSS_SCALE (1.0f / 4194304.0f)
#define MARG 0.5f          // R3-proven screening margin
#define CAND_CAP 512

typedef __attribute__((ext_vector_type(8))) short short8;
typedef _Float16 half8 __attribute__((ext_vector_type(8)));
typedef __attribute__((ext_vector_type(4))) float f32x4;

__device__ __forceinline__ unsigned short f2bf(float f) {
    unsigned u = __float_as_uint(f);
    u += 0x7FFF + ((u >> 16) & 1);          // RN-even to bf16
    return (unsigned short)(u >> 16);
}
__device__ __forceinline__ float bf2f(unsigned short h) {
    return __uint_as_float((unsigned)h << 16);
}

__global__ void zero_loss_kernel(float* __restrict__ loss) { *loss = 0.0f; }

__global__ __launch_bounds__(256) void e2_kernel(
    const float* __restrict__ codebook, float* __restrict__ e2)
{
    const int c = blockIdx.x * 256 + threadIdx.x;
    const float4* row = (const float4*)(codebook + (long)c * OUT_DIM);
    float s = 0.0f;
    #pragma unroll
    for (int m = 0; m < 16; ++m) {
        const float4 v = row[m];
        s += v.x * v.x + v.y * v.y + v.z * v.z + v.w * v.w;
    }
    e2[c] = s;
}

// Permute codebook into MFMA B-fragment order, split hi/lo bf16 (R3-verified).
__global__ __launch_bounds__(256) void prep_cb(
    const float* __restrict__ cb,
    unsigned short* __restrict__ cbh, unsigned short* __restrict__ cbl)
{
    const int id = blockIdx.x * 256 + threadIdx.x;  // 0..4095: (code n, half h)
    const int n = id >> 1, h = id & 1;
    const int t = n >> 4, l15 = n & 15;
    const float* src = cb + (long)n * OUT_DIM + h * 32;
    #pragma unroll
    for (int quad = 0; quad < 4; ++quad) {
        short8 hi, lo;
        #pragma unroll
        for (int j = 0; j < 8; ++j) {
            const float f = src[quad * 8 + j];
            const unsigned short hb = f2bf(f);
            hi[j] = (short)hb;
            lo[j] = (short)f2bf(f - bf2f(hb));
        }
        const long dst = ((long)(t * 2 + h) * 64 + quad * 16 + l15) * 8;
        *(short8*)(cbh + dst) = hi;
        *(short8*)(cbl + dst) = lo;
    }
}

// Permute W1/W2/W3 into MFMA B-frag order, fp16 hi/lo split.
// frag[lane][j] = W[kc*32 + (lane>>4)*8 + j][nt*16 + (lane&15)], frag = kc*4+nt
__global__ __launch_bounds__(256) void prep_w(
    const float* __restrict__ W1, const float* __restrict__ W2,
    const float* __restrict__ W3,
    _Float16* __restrict__ w1h, _Float16* __restrict__ w1l,
    _Float16* __restrict__ w2h, _Float16* __restrict__ w2l,
    _Float16* __restrict__ w3h, _Float16* __restrict__ w3l)
{
    const int id = blockIdx.x * 256 + threadIdx.x;   // 0..2047
    const int lane = id & 63;
    const int m = lane & 15, quad = lane >> 4;
    const float* W; _Float16 *dh, *dl; int frag;
    if (id < 1024)      { W = W1; dh = w1h; dl = w1l; frag = id >> 6; }          // 16 frags
    else if (id < 1536) { W = W2; dh = w2h; dl = w2l; frag = (id - 1024) >> 6; } // 8
    else                { W = W3; dh = w3h; dl = w3l; frag = (id - 1536) >> 6; } // 8
    const int kc = frag >> 2, nt = frag & 3;
    half8 hi, lo;
    #pragma unroll
    for (int j = 0; j < 8; ++j) {
        const float v = W[(long)(kc * 32 + quad * 8 + j) * 64 + nt * 16 + m];
        hi[j] = (_Float16)v;
        lo[j] = (_Float16)(v - (float)hi[j]);
    }
    const long dst = (long)(frag * 64 + lane) * 8;
    *(half8*)(dh + dst) = hi;
    *(half8*)(dl + dst) = lo;
}

#define MFMA16(A, B, C) __builtin_amdgcn_mfma_f32_16x16x32_f16(A, B, C, 0, 0, 0)

__device__ __forceinline__ void split16(const float* xs, half8& h, half8& l) {
    #pragma unroll
    for (int j = 0; j < 8; ++j) {
        h[j] = (_Float16)xs[j];
        l[j] = (_Float16)(xs[j] - (float)h[j]);
    }
}

// ---------------- MLP via MFMA: 64 pts/block, 256 thr = 4 waves -------------
// Wave w owns points w*16..w*16+15 end-to-end; LDS traffic is wave-local so
// no barriers until the final cross-wave coalesced store.
__global__ __launch_bounds__(256) void mlp_mfma(
    const float* __restrict__ obs,
    const float* __restrict__ b1, const float* __restrict__ b2,
    const float* __restrict__ b3,
    const _Float16* __restrict__ w1h, const _Float16* __restrict__ w1l,
    const _Float16* __restrict__ w2h, const _Float16* __restrict__ w2l,
    const _Float16* __restrict__ w3h, const _Float16* __restrict__ w3l,
    float* __restrict__ xout)
{
    __shared__ float hbuf[64 * 68];     // stride 68: <=2-way banks (free)
    const int t = threadIdx.x, lane = t & 63, w = t >> 6;
    const int m = lane & 15, quad = lane >> 4;
    const long base = (long)blockIdx.x * 64;
    const int row0 = w * 16 + quad * 4;         // C-layout write rows (+r)
    const int arow_l = w * 16 + m;              // A-layout read row

    float bb1[4], bb2[4], bb3[4];
    #pragma unroll
    for (int nt = 0; nt < 4; ++nt) {
        bb1[nt] = b1[nt * 16 + m];
        bb2[nt] = b2[nt * 16 + m];
        bb3[nt] = b3[nt * 16 + m];
    }

    // ---- A-frags from obs (fp16 split), K = 128 -> 4 chunks ----
    const float* arow = obs + (base + w * 16 + m) * IN_DIM;
    half8 a1h[4], a1l[4];
    #pragma unroll
    for (int kc = 0; kc < 4; ++kc) {
        const float4 va = *(const float4*)(arow + kc * 32 + quad * 8);
        const float4 vb = *(const float4*)(arow + kc * 32 + quad * 8 + 4);
        const float xs[8] = {va.x, va.y, va.z, va.w, vb.x, vb.y, vb.z, vb.w};
        split16(xs, a1h[kc], a1l[kc]);
    }

    // ---- layer 1: [64x128]x[128x64] + b1, relu ----
    #pragma unroll
    for (int nt = 0; nt < 4; ++nt) {
        f32x4 acc = {0.0f, 0.0f, 0.0f, 0.0f};
        #pragma unroll
        for (int kc = 0; kc < 4; ++kc) {
            const long fo = (long)((kc * 4 + nt) * 64 + lane) * 8;
            const half8 wh = *(const half8*)(w1h + fo);
            const half8 wl = *(const half8*)(w1l + fo);
            acc = MFMA16(a1h[kc], wh, acc);
            acc = MFMA16(a1l[kc], wh, acc);
            acc = MFMA16(a1h[kc], wl, acc);
        }
        #pragma unroll
        for (int r = 0; r < 4; ++r) {
            const float v = acc[r] + bb1[nt];
            hbuf[(row0 + r) * 68 + nt * 16 + m] = v > 0.0f ? v : 0.0f;
        }
    }

    // ---- layer 2: [64x64]x[64x64] + b2, relu (A re-split from LDS) ----
    half8 a2h[2], a2l[2];
    #pragma unroll
    for (int kc = 0; kc < 2; ++kc) {
        const float4 va = *(const float4*)&hbuf[arow_l * 68 + kc * 32 + quad * 8];
        const float4 vb = *(const float4*)&hbuf[arow_l * 68 + kc * 32 + quad * 8 + 4];
        const float xs[8] = {va.x, va.y, va.z, va.w, vb.x, vb.y, vb.z, vb.w};
        split16(xs, a2h[kc], a2l[kc]);
    }
    #pragma unroll
    for (int nt = 0; nt < 4; ++nt) {
        f32x4 acc = {0.0f, 0.0f, 0.0f, 0.0f};
        #pragma unroll
        for (int kc = 0; kc < 2; ++kc) {
            const long fo = (long)((kc * 4 + nt) * 64 + lane) * 8;
            const half8 wh = *(const half8*)(w2h + fo);
            const half8 wl = *(const half8*)(w2l + fo);
            acc = MFMA16(a2h[kc], wh, acc);
            acc = MFMA16(a2l[kc], wh, acc);
            acc = MFMA16(a2h[kc], wl, acc);
        }
        #pragma unroll
        for (int r = 0; r < 4; ++r) {
            const float v = acc[r] + bb2[nt];
            hbuf[(row0 + r) * 68 + nt * 16 + m] = v > 0.0f ? v : 0.0f;
        }
    }

    // ---- layer 3: [64x64]x[64x64] + b3 (no relu) ----
    half8 a3h[2], a3l[2];
    #pragma unroll
    for (int kc = 0; kc < 2; ++kc) {
        const float4 va = *(const float4*)&hbuf[arow_l * 68 + kc * 32 + quad * 8];
        const float4 vb = *(const float4*)&hbuf[arow_l * 68 + kc * 32 + quad * 8 + 4];
        const float xs[8] = {va.x, va.y, va.z, va.w, vb.x, vb.y, vb.z, vb.w};
        split16(xs, a3h[kc], a3l[kc]);
    }
    #pragma unroll
    for (int nt = 0; nt < 4; ++nt) {
        f32x4 acc = {0.0f, 0.0f, 0.0f, 0.0f};
        #pragma unroll
        for (int kc = 0; kc < 2; ++kc) {
            const long fo = (long)((kc * 4 + nt) * 64 + lane) * 8;
            const half8 wh = *(const half8*)(w3h + fo);
            const half8 wl = *(const half8*)(w3l + fo);
            acc = MFMA16(a3h[kc], wh, acc);
            acc = MFMA16(a3l[kc], wh, acc);
            acc = MFMA16(a3h[kc], wl, acc);
        }
        #pragma unroll
        for (int r = 0; r < 4; ++r)
            hbuf[(row0 + r) * 68 + nt * 16 + m] = acc[r] + bb3[nt];
    }
    __syncthreads();    // only cross-wave touch: coalesced store below

    float4* og = (float4*)(xout + base * OUT_DIM);
    #pragma unroll
    for (int mm = 0; mm < 4; ++mm) {
        const int v = t + 256 * mm;
        const int p = v >> 4, k4 = v & 15;
        og[v] = *(const float4*)&hbuf[p * 68 + k4 * 4];
    }
}

// exact fp32 distance update (R2/R3 proven numerics)
__device__ __forceinline__ void exact_upd(
    const float* __restrict__ xr, const float* __restrict__ cb,
    const float* __restrict__ e2, int n, float& bd, int& bi)
{
    const float4* xp = (const float4*)xr;
    const float4* cp = (const float4*)(cb + (long)n * OUT_DIM);
    float a0 = 0.0f, a1 = 0.0f;
    #pragma unroll
    for (int m = 0; m < 16; ++m) {
        const float4 xv = xp[m], cv = cp[m];
        a0 = fmaf(xv.x, cv.x, a0); a1 = fmaf(xv.y, cv.y, a1);
        a0 = fmaf(xv.z, cv.z, a0); a1 = fmaf(xv.w, cv.w, a1);
    }
    const float ex = fmaf(-2.0f, a0 + a1, e2[n]);
    if (ex < bd || (ex == bd && n < bi)) { bd = ex; bi = n; }
}

// ---------------- VQ via MFMA: R3 VERBATIM (measured 156 us, passed) --------
__global__ __launch_bounds__(256) void vq_mfma(
    const float* __restrict__ cb,
    const unsigned short* __restrict__ cbhp,
    const unsigned short* __restrict__ cblp,
    const float* __restrict__ e2,
    float* __restrict__ msg,        // in: x, out: quantize
    float* __restrict__ idx_out,
    float* __restrict__ loss_out)
{
    __shared__ float best_d_s[4][16][16];   // [wave][pt][col]
    __shared__ int   best_i_s[4][16][16];
    __shared__ int   cand_pc[CAND_CAP];     // (p_local<<16) | code
    __shared__ float cand_d[CAND_CAP];
    __shared__ int   cand_cnt;
    __shared__ int   idx_sh[64];
    __shared__ float wred[4];

    const int t = threadIdx.x, lane = t & 63, w = t >> 6;
    const int m = lane & 15, quad = lane >> 4;
    const long base = (long)blockIdx.x * 64;

    if (t == 0) cand_cnt = 0;

    // A-frags: x[point = w*16 + m][k = quad*8 + j], halves k0=0/32. Built once.
    const float* xrow = msg + (base + w * 16 + m) * OUT_DIM;
    short8 a0h, a0l, a1h, a1l;
    {
        const float4 xa = *(const float4*)(xrow + quad * 8);
        const float4 xb = *(const float4*)(xrow + quad * 8 + 4);
        const float4 xc = *(const float4*)(xrow + 32 + quad * 8);
        const float4 xd = *(const float4*)(xrow + 32 + quad * 8 + 4);
        const float x0[8] = {xa.x, xa.y, xa.z, xa.w, xb.x, xb.y, xb.z, xb.w};
        const float x1[8] = {xc.x, xc.y, xc.z, xc.w, xd.x, xd.y, xd.z, xd.w};
        #pragma unroll
        for (int j = 0; j < 8; ++j) {
            unsigned short hb = f2bf(x0[j]);
            a0h[j] = (short)hb; a0l[j] = (short)f2bf(x0[j] - bf2f(hb));
            hb = f2bf(x1[j]);
            a1h[j] = (short)hb; a1l[j] = (short)f2bf(x1[j] - bf2f(hb));
        }
    }
    __syncthreads();   // cand_cnt visible

    float bd[4] = {3.4e38f, 3.4e38f, 3.4e38f, 3.4e38f};
    int   bi[4] = {0, 0, 0, 0};

    // register double-buffered B-frags
    long toff = (long)lane * 8;
    short8 bh0 = *(const short8*)(cbhp + toff);
    short8 bh1 = *(const short8*)(cbhp + toff + 512);
    short8 bl0 = *(const short8*)(cblp + toff);
    short8 bl1 = *(const short8*)(cblp + toff + 512);

    for (int tile = 0; tile < 128; ++tile) {
        const int nt = (tile + 1 < 128) ? tile + 1 : 127;
        const long noff = (long)nt * 1024 + (long)lane * 8;
        const short8 nh0 = *(const short8*)(cbhp + noff);
        const short8 nh1 = *(const short8*)(cbhp + noff + 512);
        const short8 nl0 = *(const short8*)(cblp + noff);
        const short8 nl1 = *(const short8*)(cblp + noff + 512);
        const float e2v = e2[tile * 16 + m];

        f32x4 acc0 = {0.0f, 0.0f, 0.0f, 0.0f};
        f32x4 acc1 = {0.0f, 0.0f, 0.0f, 0.0f};
        acc0 = __builtin_amdgcn_mfma_f32_16x16x32_bf16(a0h, bh0, acc0, 0, 0, 0);
        acc1 = __builtin_amdgcn_mfma_f32_16x16x32_bf16(a1h, bh1, acc1, 0, 0, 0);
        acc0 = __builtin_amdgcn_mfma_f32_16x16x32_bf16(a0l, bh0, acc0, 0, 0, 0);
        acc1 = __builtin_amdgcn_mfma_f32_16x16x32_bf16(a1l, bh1, acc1, 0, 0, 0);
        acc0 = __builtin_amdgcn_mfma_f32_16x16x32_bf16(a0h, bl0, acc0, 0, 0, 0);
        acc1 = __builtin_amdgcn_mfma_f32_16x16x32_bf16(a1h, bl1, acc1, 0, 0, 0);

        const int code = tile * 16 + m;
        #pragma unroll
        for (int r = 0; r < 4; ++r) {
            const float d = fmaf(-2.0f, acc0[r] + acc1[r], e2v);
            if (d < bd[r]) {
                if (bd[r] < d + MARG) {                 // near-tie supersession
                    const int slot = atomicAdd(&cand_cnt, 1);
                    if (slot < CAND_CAP) {
                        cand_pc[slot] = ((w * 16 + quad * 4 + r) << 16) | bi[r];
                        cand_d[slot] = bd[r];
                    }
                }
                bd[r] = d; bi[r] = code;
            } else if (d < bd[r] + MARG) {              // within margin of run-min
                const int slot = atomicAdd(&cand_cnt, 1);
                if (slot < CAND_CAP) {
                    cand_pc[slot] = ((w * 16 + quad * 4 + r) << 16) | code;
                    cand_d[slot] = d;
                }
            }
        }
        bh0 = nh0; bh1 = nh1; bl0 = nl0; bl1 = nl1;
    }

    // publish per-slot bests: point row = quad*4 + r, col = m
    #pragma unroll
    for (int r = 0; r < 4; ++r) {
        best_d_s[w][quad * 4 + r][m] = bd[r];
        best_i_s[w][quad * 4 + r][m] = bi[r];
    }
    __syncthreads();

    // exact-rescore stage: one thread per point
    if (t < 64) {
        const int p = t, ww = p >> 4, pi = p & 15;
        float dmin = 3.4e38f;
        #pragma unroll
        for (int c = 0; c < 16; ++c) dmin = fminf(dmin, best_d_s[ww][pi][c]);
        const float thr = dmin + MARG;

        float fbd = 3.4e38f; int fbi = 1 << 30;
        const float* xr = msg + (base + p) * OUT_DIM;   // still x
        #pragma unroll
        for (int c = 0; c < 16; ++c)
            if (best_d_s[ww][pi][c] <= thr)
                exact_upd(xr, cb, e2, best_i_s[ww][pi][c], fbd, fbi);
        const int L = min(cand_cnt, CAND_CAP);
        for (int l = 0; l < L; ++l) {
            const int pc = cand_pc[l];
            if ((pc >> 16) == p && cand_d[l] <= thr)
                exact_upd(xr, cb, e2, pc & 0xFFFF, fbd, fbi);
        }
        idx_sh[p] = fbi;
        idx_out[base + p] = (float)fbi;
    }
    __syncthreads();

    // gather q, write msg, accumulate loss (read-x / write-q same thread+addr)
    float lsum = 0.0f;
    float4* xg = (float4*)(msg + base * OUT_DIM);
    #pragma unroll
    for (int mm = 0; mm < 4; ++mm) {
        const int v = t + 256 * mm;
        const int p = v >> 4, k4 = v & 15;
        const int code = idx_sh[p];
        const float4 q = ((const float4*)(cb + (long)code * OUT_DIM))[k4];
        const float4 xv = xg[v];
        const float dx = q.x - xv.x, dy = q.y - xv.y;
        const float dz = q.z - xv.z, dw2 = q.w - xv.w;
        lsum += dx * dx + dy * dy + dz * dz + dw2 * dw2;
        xg[v] = q;
    }
    #pragma unroll
    for (int off = 32; off > 0; off >>= 1) lsum += __shfl_down(lsum, off, 64);
    if (lane == 0) wred[w] = lsum;
    __syncthreads();
    if (t == 0)
        atomicAdd(loss_out, (wred[0] + wred[1] + wred[2] + wred[3]) * LOSS_SCALE);
}

extern "C" void kernel_launch(void* const* d_in, const int* in_sizes, int n_in,
                              void* d_out, int out_size, void* d_ws, size_t ws_size,
                              hipStream_t stream) {
    const float* obs = (const float*)d_in[0];
    const float* W1  = (const float*)d_in[1];
    const float* b1  = (const float*)d_in[2];
    const float* W2  = (const float*)d_in[3];
    const float* b2  = (const float*)d_in[4];
    const float* W3  = (const float*)d_in[5];
    const float* b3  = (const float*)d_in[6];
    const float* cb  = (const float*)d_in[7];

    float* out  = (float*)d_out;
    float* msg  = out;                        // also x staging
    float* idxf = out + MSG_ELEMS;
    float* loss = out + MSG_ELEMS + NPTS;

    char* ws = (char*)d_ws;
    float*          e2  = (float*)ws;                          // 8 KB
    unsigned short* cbh = (unsigned short*)(ws + 8192);        // 256 KB
    unsigned short* cbl = (unsigned short*)(ws + 270336);      // 256 KB
    _Float16* w1h = (_Float16*)(ws + 532480);                  // 16 KB
    _Float16* w1l = (_Float16*)(ws + 548864);                  // 16 KB
    _Float16* w2h = (_Float16*)(ws + 565248);                  // 8 KB
    _Float16* w2l = (_Float16*)(ws + 573440);                  // 8 KB
    _Float16* w3h = (_Float16*)(ws + 581632);                  // 8 KB
    _Float16* w3l = (_Float16*)(ws + 589824);                  // 8 KB

    zero_loss_kernel<<<1, 1, 0, stream>>>(loss);
    e2_kernel<<<CB_N / 256, 256, 0, stream>>>(cb, e2);
    prep_cb<<<16, 256, 0, stream>>>(cb, cbh, cbl);
    prep_w<<<8, 256, 0, stream>>>(W1, W2, W3, w1h, w1l, w2h, w2l, w3h, w3l);
    mlp_mfma<<<NPTS / 64, 256, 0, stream>>>(obs, b1, b2, b3,
                                            w1h, w1l, w2h, w2l, w3h, w3l, msg);
    vq_mfma<<<NPTS / 64, 256, 0, stream>>>(cb, cbh, cbl, e2, msg, idxf, loss);
}